// Round 12
// baseline (133.748 us; speedup 1.0000x reference)
//
#include <hip/hip_runtime.h>

// Problem constants: B=2, L=8192, D=1024, f32 in/out.
#define BB 2
#define LL 8192
#define DD 1024
#define NC 128        // time chunks
#define TT 64         // chunk length (2^6)
#define NPAIR (DD/2)  // 512 d-pairs; one thread <-> one d-pair (8 B/lane)
#define NCOL (NPAIR/256)   // 2 pair-columns
#define FOLD_BATCH 16

// ph = exp(-(pr^2+pi^2)) * exp(i*atan2(pi,pr))
__device__ __forceinline__ void compute_ph(float pr, float pi, float& phr, float& phi) {
    float r2 = fmaf(pr, pr, pi * pi);
    float mag = expf(-r2);
    float r = sqrtf(r2);
    if (r > 1e-30f) {
        float inv = mag / r;
        phr = pr * inv;
        phi = pi * inv;
    } else {
        phr = mag;  // atan2(0,0)=0 -> phase 1+0i
        phi = 0.0f;
    }
}

// Single-kernel decoupled lookback, spill-free:
//   phase 1: stream x chunk (float2), zero-init partial -> publish flag
//   wait:    thread u polls flag[u], u < j (parallel; predecessors all
//            resident: 1024 blocks @ launch_bounds(256,4) -> 4/CU x 256 CU)
//   phase 2: fold predecessors' partials (16-deep clamped batches)
//   phase 3: re-read own x chunk (own-XCD L2/L3 hot), replay, write out
// x is NOT held in registers across the wait -> no scratch spill (R9 bug).
__global__ __launch_bounds__(256, 4) void k_fused(
    const float* __restrict__ x,
    const float* __restrict__ pr, const float* __restrict__ pi,
    const float* __restrict__ qr, const float* __restrict__ qi,
    const float* __restrict__ lr, const float* __restrict__ li,
    float4* __restrict__ partial,
    unsigned int* __restrict__ flags,   // [BB*NCOL][NC]
    float* __restrict__ out)
{
    const int tid = threadIdx.x;
    const int p   = blockIdx.x * 256 + tid;   // d-pair 0..511
    const int j   = blockIdx.y;
    const int b   = blockIdx.z;
    const int d0  = 2 * p, d1 = d0 + 1;
    unsigned int* colflags = flags + ((size_t)b * NCOL + blockIdx.x) * NC;

    float phr0, phi0, phr1, phi1;
    compute_ph(pr[d0], pi[d0], phr0, phi0);
    compute_ph(pr[d1], pi[d1], phr1, phi1);
    const float q0r = qr[d0], q0i = qi[d0], q1r = qr[d1], q1i = qi[d1];

    const size_t rowbase = (size_t)b * LL + (size_t)j * TT;
    const float2* xp = (const float2*)(x + rowbase * DD) + p;

    // ---- phase 1: zero-init chunk partial (streaming read of x) ----
    {
        float sr0 = 0.f, si0 = 0.f, sr1 = 0.f, si1 = 0.f;
        #pragma unroll 32
        for (int t = 0; t < TT; ++t) {
            float2 xv = xp[(size_t)t * NPAIR];
            float nr0 = fmaf(phr0, sr0, fmaf(-phi0, si0, q0r * xv.x));
            float ni0 = fmaf(phi0, sr0, fmaf(phr0, si0, q0i * xv.x));
            float nr1 = fmaf(phr1, sr1, fmaf(-phi1, si1, q1r * xv.y));
            float ni1 = fmaf(phi1, sr1, fmaf(phr1, si1, q1i * xv.y));
            sr0 = nr0; si0 = ni0; sr1 = nr1; si1 = ni1;
        }
        partial[((size_t)b * NC + j) * NPAIR + p] = make_float4(sr0, si0, sr1, si1);
    }

    // ---- publish: partial visible device-wide, then set this chunk's flag ----
    __syncthreads();
    if (tid == 0) {
        __threadfence();   // release
        __hip_atomic_store(&colflags[j], 1u, __ATOMIC_RELEASE, __HIP_MEMORY_SCOPE_AGENT);
    }

    // ---- wait: parallel poll of predecessor flags (thread u <-> flag u) ----
    if (tid < j) {
        while (__hip_atomic_load(&colflags[tid], __ATOMIC_ACQUIRE,
                                 __HIP_MEMORY_SCOPE_AGENT) == 0u) {
            __builtin_amdgcn_s_sleep(2);
        }
    }
    __syncthreads();
    __threadfence();       // acquire side, block-wide

    // ---- phase 2: a = ph^TT (6 squarings); fold partials 0..j-1 ----
    float a0r = phr0, a0i = phi0, a1r = phr1, a1i = phi1;
    #pragma unroll
    for (int k = 0; k < 6; ++k) {
        float n0r = a0r * a0r - a0i * a0i, n0i = 2.f * a0r * a0i;
        float n1r = a1r * a1r - a1i * a1i, n1i = 2.f * a1r * a1i;
        a0r = n0r; a0i = n0i; a1r = n1r; a1i = n1i;
    }

    float S0r = lr[d0], S0i = li[d0], S1r = lr[d1], S1i = li[d1];
    const float4* pb = partial + (size_t)b * NC * NPAIR + p;
    for (int bs = 0; bs < j; bs += FOLD_BATCH) {
        float4 buf[FOLD_BATCH];
        #pragma unroll
        for (int u = 0; u < FOLD_BATCH; ++u) {
            int k = bs + u;
            int kc = (k < j) ? k : (j - 1);   // clamp: always a valid address
            buf[u] = pb[(size_t)kc * NPAIR];
        }
        #pragma unroll
        for (int u = 0; u < FOLD_BATCH; ++u) {
            int k = bs + u;
            if (k < j) {                       // uniform per block
                float n0r = fmaf(a0r, S0r, fmaf(-a0i, S0i, buf[u].x));
                float n0i = fmaf(a0i, S0r, fmaf(a0r, S0i, buf[u].y));
                float n1r = fmaf(a1r, S1r, fmaf(-a1i, S1i, buf[u].z));
                float n1i = fmaf(a1i, S1r, fmaf(a1r, S1i, buf[u].w));
                S0r = n0r; S0i = n0i; S1r = n1r; S1i = n1i;
            }
        }
    }

    // ---- phase 3: re-read own x chunk (cache-hot), replay, write out ----
    float2* op = (float2*)(out + rowbase * DD) + p;
    #pragma unroll 16
    for (int t = 0; t < TT; ++t) {
        float2 xv = xp[(size_t)t * NPAIR];
        float n0r = fmaf(phr0, S0r, fmaf(-phi0, S0i, q0r * xv.x));
        float n0i = fmaf(phi0, S0r, fmaf(phr0, S0i, q0i * xv.x));
        float n1r = fmaf(phr1, S1r, fmaf(-phi1, S1i, q1r * xv.y));
        float n1i = fmaf(phi1, S1r, fmaf(phr1, S1i, q1i * xv.y));
        S0r = n0r; S0i = n0i; S1r = n1r; S1i = n1i;
        op[(size_t)t * NPAIR] = make_float2(n0r, n1r);
    }
}

extern "C" void kernel_launch(void* const* d_in, const int* in_sizes, int n_in,
                              void* d_out, int out_size, void* d_ws, size_t ws_size,
                              hipStream_t stream) {
    const float* x  = (const float*)d_in[0];
    const float* pr = (const float*)d_in[1];
    const float* pi = (const float*)d_in[2];
    const float* qr = (const float*)d_in[3];
    const float* qi = (const float*)d_in[4];
    const float* lr = (const float*)d_in[5];
    const float* li = (const float*)d_in[6];
    float* out = (float*)d_out;

    unsigned int* flags = (unsigned int*)d_ws;            // BB*NCOL*NC*4 = 2 KB
    float4* partial = (float4*)((char*)d_ws + 8192);      // BB*NC*NPAIR*16 = 2 MB

    // reset flags every call (graph-capture-safe async memset)
    hipMemsetAsync(d_ws, 0, 8192, stream);

    dim3 grid(NCOL, NC, BB);   // 2 x 128 x 2 = 512 blocks
    k_fused<<<grid, 256, 0, stream>>>(x, pr, pi, qr, qi, lr, li, partial, flags, out);
}

// Round 13
// 63.826 us; speedup vs baseline: 2.0955x; 2.0955x over previous
//
#include <hip/hip_runtime.h>

// Problem constants: B=2, L=8192, D=1024, f32 in/out.
#define BB 2
#define LL 8192
#define DD 1024
#define NC 128        // time chunks
#define TT 64         // chunk length (2^6)
#define NQ (DD/4)     // 256 d-quads; one thread <-> one quad (16 B/lane)
#define FB 8          // fold batch (x2 half-arrays -> 16 loads in flight)

// ph = exp(-(pr^2+pi^2)) * exp(i*atan2(pi,pr))
__device__ __forceinline__ void compute_ph(float pr, float pi, float& phr, float& phi) {
    float r2 = fmaf(pr, pr, pi * pi);
    float mag = expf(-r2);
    float r = sqrtf(r2);
    if (r > 1e-30f) {
        float inv = mag / r;
        phr = pr * inv;
        phi = pi * inv;
    } else {
        phr = mag;  // atan2(0,0)=0 -> phase 1+0i
        phi = 0.0f;
    }
}

#define CSTEP(c) \
    { float nr = fmaf(ph##c##r, s##c##r, fmaf(-ph##c##i, s##c##i, q##c##r * xc##c)); \
      float ni = fmaf(ph##c##i, s##c##r, fmaf( ph##c##r, s##c##i, q##c##i * xc##c)); \
      s##c##r = nr; s##c##i = ni; }

// Pass 1: zero-init chunk end-state. Pure float4 read stream over x.
__global__ __launch_bounds__(128) void k_partial(
    const float* __restrict__ x,
    const float* __restrict__ pr, const float* __restrict__ pi,
    const float* __restrict__ qr, const float* __restrict__ qi,
    float4* __restrict__ partial)
{
    const int q = blockIdx.x * 128 + threadIdx.x;   // quad 0..255
    const int j = blockIdx.y;
    const int b = blockIdx.z;

    const float4 prv = ((const float4*)pr)[q], piv = ((const float4*)pi)[q];
    const float4 qrv = ((const float4*)qr)[q], qiv = ((const float4*)qi)[q];
    float ph0r, ph0i, ph1r, ph1i, ph2r, ph2i, ph3r, ph3i;
    compute_ph(prv.x, piv.x, ph0r, ph0i);
    compute_ph(prv.y, piv.y, ph1r, ph1i);
    compute_ph(prv.z, piv.z, ph2r, ph2i);
    compute_ph(prv.w, piv.w, ph3r, ph3i);
    const float q0r = qrv.x, q0i = qiv.x, q1r = qrv.y, q1i = qiv.y;
    const float q2r = qrv.z, q2i = qiv.z, q3r = qrv.w, q3i = qiv.w;

    const float4* xq = (const float4*)(x + ((size_t)b * LL + (size_t)j * TT) * DD) + q;

    float s0r = 0.f, s0i = 0.f, s1r = 0.f, s1i = 0.f;
    float s2r = 0.f, s2i = 0.f, s3r = 0.f, s3i = 0.f;
    #pragma unroll 16
    for (int t = 0; t < TT; ++t) {
        float4 xv = xq[(size_t)t * NQ];
        float xc0 = xv.x, xc1 = xv.y, xc2 = xv.z, xc3 = xv.w;
        CSTEP(0) CSTEP(1) CSTEP(2) CSTEP(3)
    }
    // layout: [b][k][h][NQ], h=0 -> channels 0,1 ; h=1 -> channels 2,3
    float4* pp = partial + (((size_t)b * NC + j) * 2) * NQ + q;
    pp[0]  = make_float4(s0r, s0i, s1r, s1i);
    pp[NQ] = make_float4(s2r, s2i, s3r, s3i);
}

#define FSTEP(c, vr, vi) \
    { float nr = fmaf(a##c##r, S##c##r, fmaf(-a##c##i, S##c##i, vr)); \
      float ni = fmaf(a##c##i, S##c##r, fmaf( a##c##r, S##c##i, vi)); \
      S##c##r = nr; S##c##i = ni; }

#define RSTEP(c) \
    { float nr = fmaf(ph##c##r, S##c##r, fmaf(-ph##c##i, S##c##i, q##c##r * xc##c)); \
      float ni = fmaf(ph##c##i, S##c##r, fmaf( ph##c##r, S##c##i, q##c##i * xc##c)); \
      S##c##r = nr; S##c##i = ni; }

// Pass 2: fold partials 0..j-1 (independent batched loads, uniform trip count),
// then replay the chunk as a float4 read+write stream.
__global__ __launch_bounds__(128) void k_final(
    const float* __restrict__ x,
    const float* __restrict__ pr, const float* __restrict__ pi,
    const float* __restrict__ qr, const float* __restrict__ qi,
    const float* __restrict__ lr, const float* __restrict__ li,
    const float4* __restrict__ partial,
    float* __restrict__ out)
{
    const int q = blockIdx.x * 128 + threadIdx.x;   // quad 0..255
    const int j = blockIdx.y;
    const int b = blockIdx.z;

    const float4 prv = ((const float4*)pr)[q], piv = ((const float4*)pi)[q];
    const float4 qrv = ((const float4*)qr)[q], qiv = ((const float4*)qi)[q];
    float ph0r, ph0i, ph1r, ph1i, ph2r, ph2i, ph3r, ph3i;
    compute_ph(prv.x, piv.x, ph0r, ph0i);
    compute_ph(prv.y, piv.y, ph1r, ph1i);
    compute_ph(prv.z, piv.z, ph2r, ph2i);
    compute_ph(prv.w, piv.w, ph3r, ph3i);
    const float q0r = qrv.x, q0i = qiv.x, q1r = qrv.y, q1i = qiv.y;
    const float q2r = qrv.z, q2i = qiv.z, q3r = qrv.w, q3i = qiv.w;

    // a = ph^TT per channel (6 squarings)
    float a0r = ph0r, a0i = ph0i, a1r = ph1r, a1i = ph1i;
    float a2r = ph2r, a2i = ph2i, a3r = ph3r, a3i = ph3i;
    #pragma unroll
    for (int k = 0; k < 6; ++k) {
        float n0r = a0r*a0r - a0i*a0i, n0i = 2.f*a0r*a0i;
        float n1r = a1r*a1r - a1i*a1i, n1i = 2.f*a1r*a1i;
        float n2r = a2r*a2r - a2i*a2i, n2i = 2.f*a2r*a2i;
        float n3r = a3r*a3r - a3i*a3i, n3i = 2.f*a3r*a3i;
        a0r = n0r; a0i = n0i; a1r = n1r; a1i = n1i;
        a2r = n2r; a2i = n2i; a3r = n3r; a3i = n3i;
    }

    const float4 lrv = ((const float4*)lr)[q], liv = ((const float4*)li)[q];
    float S0r = lrv.x, S0i = liv.x, S1r = lrv.y, S1i = liv.y;
    float S2r = lrv.z, S2i = liv.z, S3r = lrv.w, S3i = liv.w;

    // fold: S <- a*S + P_k, k = 0..j-1 (clamped batched loads, uniform guard)
    const float4* pb = partial + ((size_t)b * NC * 2) * NQ + q;
    for (int bs = 0; bs < j; bs += FB) {
        float4 bufA[FB], bufB[FB];
        #pragma unroll
        for (int u = 0; u < FB; ++u) {
            int k = bs + u;
            int kc = (k < j) ? k : (j - 1);
            bufA[u] = pb[(size_t)kc * 2 * NQ];
            bufB[u] = pb[(size_t)kc * 2 * NQ + NQ];
        }
        #pragma unroll
        for (int u = 0; u < FB; ++u) {
            if (bs + u < j) {
                FSTEP(0, bufA[u].x, bufA[u].y)
                FSTEP(1, bufA[u].z, bufA[u].w)
                FSTEP(2, bufB[u].x, bufB[u].y)
                FSTEP(3, bufB[u].z, bufB[u].w)
            }
        }
    }

    // replay chunk from true start state: float4 in, float4 out
    const size_t rowbase = (size_t)b * LL + (size_t)j * TT;
    const float4* xq = (const float4*)(x + rowbase * DD) + q;
    float4* oq = (float4*)(out + rowbase * DD) + q;
    #pragma unroll 16
    for (int t = 0; t < TT; ++t) {
        float4 xv = xq[(size_t)t * NQ];
        float xc0 = xv.x, xc1 = xv.y, xc2 = xv.z, xc3 = xv.w;
        RSTEP(0) RSTEP(1) RSTEP(2) RSTEP(3)
        oq[(size_t)t * NQ] = make_float4(S0r, S1r, S2r, S3r);
    }
}

extern "C" void kernel_launch(void* const* d_in, const int* in_sizes, int n_in,
                              void* d_out, int out_size, void* d_ws, size_t ws_size,
                              hipStream_t stream) {
    const float* x  = (const float*)d_in[0];
    const float* pr = (const float*)d_in[1];
    const float* pi = (const float*)d_in[2];
    const float* qr = (const float*)d_in[3];
    const float* qi = (const float*)d_in[4];
    const float* lr = (const float*)d_in[5];
    const float* li = (const float*)d_in[6];
    float* out = (float*)d_out;

    float4* partial = (float4*)d_ws;   // BB*NC*2*NQ float4 = 2 MB

    dim3 grid(NQ / 128, NC, BB);       // 2 x 128 x 2 = 512 blocks
    k_partial<<<grid, 128, 0, stream>>>(x, pr, pi, qr, qi, partial);
    k_final<<<grid, 128, 0, stream>>>(x, pr, pi, qr, qi, lr, li, partial, out);
}

// Round 14
// 61.566 us; speedup vs baseline: 2.1724x; 1.0367x over previous
//
#include <hip/hip_runtime.h>

// Problem constants: B=2, L=8192, D=1024, f32 in/out.
#define BB 2
#define LL 8192
#define DD 1024
#define NC 256        // time chunks (more TLP: 1024 blocks, 16 waves/CU)
#define TT 32         // chunk length (2^5)
#define NPAIR (DD/2)  // 512 d-pairs; one thread <-> one d-pair (8 B/lane)
#define FOLD_BATCH 16

// ph = exp(-(pr^2+pi^2)) * exp(i*atan2(pi,pr))
__device__ __forceinline__ void compute_ph(float pr, float pi, float& phr, float& phi) {
    float r2 = fmaf(pr, pr, pi * pi);
    float mag = expf(-r2);
    float r = sqrtf(r2);
    if (r > 1e-30f) {
        float inv = mag / r;
        phr = pr * inv;
        phi = pi * inv;
    } else {
        phr = mag;  // atan2(0,0)=0 -> phase 1+0i
        phi = 0.0f;
    }
}

// ---- 8-deep double-buffered streaming macros (static indices only) ----
// LD8: issue 8 independent loads into a named buffer.
// CP8: 8 serial recurrence steps consuming a buffer (2 channels per thread).
// ST8: 8 stores of the real parts produced by CP8.

#define LD8(buf, g) \
    { _Pragma("unroll") for (int u = 0; u < 8; ++u) \
        buf[u] = xp[(size_t)((g) * 8 + u) * NPAIR]; }

#define CP8(buf) \
    { _Pragma("unroll") for (int u = 0; u < 8; ++u) { \
        float2 xv = buf[u]; \
        float nr0 = fmaf(phr0, s0r, fmaf(-phi0, s0i, q0r * xv.x)); \
        float ni0 = fmaf(phi0, s0r, fmaf( phr0, s0i, q0i * xv.x)); \
        float nr1 = fmaf(phr1, s1r, fmaf(-phi1, s1i, q1r * xv.y)); \
        float ni1 = fmaf(phi1, s1r, fmaf( phr1, s1i, q1i * xv.y)); \
        s0r = nr0; s0i = ni0; s1r = nr1; s1i = ni1; \
        buf[u] = make_float2(nr0, nr1); } }

#define ST8(buf, g) \
    { _Pragma("unroll") for (int u = 0; u < 8; ++u) \
        op[(size_t)((g) * 8 + u) * NPAIR] = buf[u]; }

// Pass 1: zero-init chunk end-state (read stream over x, 8-deep prefetch).
__global__ __launch_bounds__(256) void k_partial(
    const float* __restrict__ x,
    const float* __restrict__ pr, const float* __restrict__ pi,
    const float* __restrict__ qr, const float* __restrict__ qi,
    float4* __restrict__ partial)
{
    const int p = blockIdx.x * 256 + threadIdx.x;   // d-pair 0..511
    const int j = blockIdx.y;
    const int b = blockIdx.z;
    const int d0 = 2 * p, d1 = d0 + 1;

    float phr0, phi0, phr1, phi1;
    compute_ph(pr[d0], pi[d0], phr0, phi0);
    compute_ph(pr[d1], pi[d1], phr1, phi1);
    const float q0r = qr[d0], q0i = qi[d0], q1r = qr[d1], q1i = qi[d1];

    const float2* xp = (const float2*)(x + ((size_t)b * LL + (size_t)j * TT) * DD) + p;

    float s0r = 0.f, s0i = 0.f, s1r = 0.f, s1i = 0.f;
    float2 bufA[8], bufB[8];
    LD8(bufA, 0); LD8(bufB, 1);   // 16 loads in flight
    CP8(bufA);    LD8(bufA, 2);
    CP8(bufB);    LD8(bufB, 3);
    CP8(bufA);
    CP8(bufB);

    partial[((size_t)b * NC + j) * NPAIR + p] = make_float4(s0r, s0i, s1r, s1i);
}

// Pass 2: fold partials 0..j-1 (16-deep clamped batches, uniform trip count),
// then replay the chunk with 8-deep prefetched read + write streams.
__global__ __launch_bounds__(256) void k_final(
    const float* __restrict__ x,
    const float* __restrict__ pr, const float* __restrict__ pi,
    const float* __restrict__ qr, const float* __restrict__ qi,
    const float* __restrict__ lr, const float* __restrict__ li,
    const float4* __restrict__ partial,
    float* __restrict__ out)
{
    const int p = blockIdx.x * 256 + threadIdx.x;   // d-pair 0..511
    const int j = blockIdx.y;
    const int b = blockIdx.z;
    const int d0 = 2 * p, d1 = d0 + 1;

    float phr0, phi0, phr1, phi1;
    compute_ph(pr[d0], pi[d0], phr0, phi0);
    compute_ph(pr[d1], pi[d1], phr1, phi1);
    const float q0r = qr[d0], q0i = qi[d0], q1r = qr[d1], q1i = qi[d1];

    // a = ph^TT by repeated squaring (TT = 2^5)
    float a0r = phr0, a0i = phi0, a1r = phr1, a1i = phi1;
    #pragma unroll
    for (int k = 0; k < 5; ++k) {
        float n0r = a0r * a0r - a0i * a0i, n0i = 2.f * a0r * a0i;
        float n1r = a1r * a1r - a1i * a1i, n1i = 2.f * a1r * a1i;
        a0r = n0r; a0i = n0i; a1r = n1r; a1i = n1i;
    }

    // fold: S = last; S <- a*S + P_k for k = 0..j-1 (uniform trip count)
    float s0r = lr[d0], s0i = li[d0], s1r = lr[d1], s1i = li[d1];
    const float4* pb = partial + (size_t)b * NC * NPAIR + p;
    for (int bs = 0; bs < j; bs += FOLD_BATCH) {
        float4 buf[FOLD_BATCH];
        #pragma unroll
        for (int u = 0; u < FOLD_BATCH; ++u) {
            int k = bs + u;
            int kc = (k < j) ? k : (j - 1);   // clamp: always a valid address
            buf[u] = pb[(size_t)kc * NPAIR];
        }
        #pragma unroll
        for (int u = 0; u < FOLD_BATCH; ++u) {
            int k = bs + u;
            if (k < j) {
                float n0r = fmaf(a0r, s0r, fmaf(-a0i, s0i, buf[u].x));
                float n0i = fmaf(a0i, s0r, fmaf( a0r, s0i, buf[u].y));
                float n1r = fmaf(a1r, s1r, fmaf(-a1i, s1i, buf[u].z));
                float n1i = fmaf(a1i, s1r, fmaf( a1r, s1i, buf[u].w));
                s0r = n0r; s0i = n0i; s1r = n1r; s1i = n1i;
            }
        }
    }

    // replay chunk from true start state; 8-deep prefetch, batched stores
    const size_t rowbase = (size_t)b * LL + (size_t)j * TT;
    const float2* xp = (const float2*)(x + rowbase * DD) + p;
    float2* op = (float2*)(out + rowbase * DD) + p;

    float2 bufA[8], bufB[8];
    LD8(bufA, 0); LD8(bufB, 1);
    CP8(bufA);    ST8(bufA, 0); LD8(bufA, 2);
    CP8(bufB);    ST8(bufB, 1); LD8(bufB, 3);
    CP8(bufA);    ST8(bufA, 2);
    CP8(bufB);    ST8(bufB, 3);
}

extern "C" void kernel_launch(void* const* d_in, const int* in_sizes, int n_in,
                              void* d_out, int out_size, void* d_ws, size_t ws_size,
                              hipStream_t stream) {
    const float* x  = (const float*)d_in[0];
    const float* pr = (const float*)d_in[1];
    const float* pi = (const float*)d_in[2];
    const float* qr = (const float*)d_in[3];
    const float* qi = (const float*)d_in[4];
    const float* lr = (const float*)d_in[5];
    const float* li = (const float*)d_in[6];
    float* out = (float*)d_out;

    float4* partial = (float4*)d_ws;   // BB*NC*NPAIR float4 = 4 MB

    dim3 grid(NPAIR / 256, NC, BB);    // 2 x 256 x 2 = 1024 blocks
    k_partial<<<grid, 256, 0, stream>>>(x, pr, pi, qr, qi, partial);
    k_final<<<grid, 256, 0, stream>>>(x, pr, pi, qr, qi, lr, li, partial, out);
}

// Round 15
// 40.055 us; speedup vs baseline: 3.3391x; 1.5370x over previous
//
#include <hip/hip_runtime.h>

// Problem constants: B=2, L=8192, D=1024, f32 in/out.
#define BB 2
#define LL 8192
#define DD 1024
#define NC 64         // time chunks  (fold traffic ~ NC^2 -> keep small)
#define TT 128        // chunk length (2^7)
#define NPAIR (DD/2)  // 512 d-pairs; one thread <-> one d-pair (8 B/lane)
#define FOLD_BATCH 16

// ph = exp(-(pr^2+pi^2)) * exp(i*atan2(pi,pr))
__device__ __forceinline__ void compute_ph(float pr, float pi, float& phr, float& phi) {
    float r2 = fmaf(pr, pr, pi * pi);
    float mag = expf(-r2);
    float r = sqrtf(r2);
    if (r > 1e-30f) {
        float inv = mag / r;
        phr = pr * inv;
        phi = pi * inv;
    } else {
        phr = mag;  // atan2(0,0)=0 -> phase 1+0i
        phi = 0.0f;
    }
}

// 8-deep streaming macros (all static indices; two named buffers = double buffer)
#define LD8(buf, g) \
    { _Pragma("unroll") for (int u = 0; u < 8; ++u) \
        buf[u] = xp[(size_t)((g) * 8 + u) * NPAIR]; }

// partial pass: consume 8, no writeback
#define CP8P(buf) \
    { _Pragma("unroll") for (int u = 0; u < 8; ++u) { \
        float2 xv = buf[u]; \
        float nr0 = fmaf(phr0, s0r, fmaf(-phi0, s0i, q0r * xv.x)); \
        float ni0 = fmaf(phi0, s0r, fmaf( phr0, s0i, q0i * xv.x)); \
        float nr1 = fmaf(phr1, s1r, fmaf(-phi1, s1i, q1r * xv.y)); \
        float ni1 = fmaf(phi1, s1r, fmaf( phr1, s1i, q1i * xv.y)); \
        s0r = nr0; s0i = ni0; s1r = nr1; s1i = ni1; } }

// final pass: consume 8, keep Re in buf for the store
#define CP8F(buf) \
    { _Pragma("unroll") for (int u = 0; u < 8; ++u) { \
        float2 xv = buf[u]; \
        float nr0 = fmaf(phr0, s0r, fmaf(-phi0, s0i, q0r * xv.x)); \
        float ni0 = fmaf(phi0, s0r, fmaf( phr0, s0i, q0i * xv.x)); \
        float nr1 = fmaf(phr1, s1r, fmaf(-phi1, s1i, q1r * xv.y)); \
        float ni1 = fmaf(phi1, s1r, fmaf( phr1, s1i, q1i * xv.y)); \
        s0r = nr0; s0i = ni0; s1r = nr1; s1i = ni1; \
        buf[u] = make_float2(nr0, nr1); } }

#define ST8(buf, g) \
    { _Pragma("unroll") for (int u = 0; u < 8; ++u) \
        op[(size_t)((g) * 8 + u) * NPAIR] = buf[u]; }

// Pass 1: zero-init chunk end-state. Read-only stream, 16 groups of 8.
__global__ __launch_bounds__(256) void k_partial(
    const float* __restrict__ x,
    const float* __restrict__ pr, const float* __restrict__ pi,
    const float* __restrict__ qr, const float* __restrict__ qi,
    float4* __restrict__ partial)
{
    const int p = blockIdx.x * 256 + threadIdx.x;   // d-pair 0..511
    const int j = blockIdx.y;
    const int b = blockIdx.z;
    const int d0 = 2 * p, d1 = d0 + 1;

    float phr0, phi0, phr1, phi1;
    compute_ph(pr[d0], pi[d0], phr0, phi0);
    compute_ph(pr[d1], pi[d1], phr1, phi1);
    const float q0r = qr[d0], q0i = qi[d0], q1r = qr[d1], q1i = qi[d1];

    const float2* xp = (const float2*)(x + ((size_t)b * LL + (size_t)j * TT) * DD) + p;

    float s0r = 0.f, s0i = 0.f, s1r = 0.f, s1i = 0.f;
    float2 bufA[8], bufB[8];
    LD8(bufA, 0);  LD8(bufB, 1);
    CP8P(bufA);    LD8(bufA, 2);
    CP8P(bufB);    LD8(bufB, 3);
    CP8P(bufA);    LD8(bufA, 4);
    CP8P(bufB);    LD8(bufB, 5);
    CP8P(bufA);    LD8(bufA, 6);
    CP8P(bufB);    LD8(bufB, 7);
    CP8P(bufA);    LD8(bufA, 8);
    CP8P(bufB);    LD8(bufB, 9);
    CP8P(bufA);    LD8(bufA, 10);
    CP8P(bufB);    LD8(bufB, 11);
    CP8P(bufA);    LD8(bufA, 12);
    CP8P(bufB);    LD8(bufB, 13);
    CP8P(bufA);    LD8(bufA, 14);
    CP8P(bufB);    LD8(bufB, 15);
    CP8P(bufA);
    CP8P(bufB);

    partial[((size_t)b * NC + j) * NPAIR + p] = make_float4(s0r, s0i, s1r, s1i);
}

// Pass 2: fold partials 0..j-1 (<=63, clamped 16-deep batches), then replay
// the chunk as a double-buffered read+write stream (16 groups of 8).
__global__ __launch_bounds__(256) void k_final(
    const float* __restrict__ x,
    const float* __restrict__ pr, const float* __restrict__ pi,
    const float* __restrict__ qr, const float* __restrict__ qi,
    const float* __restrict__ lr, const float* __restrict__ li,
    const float4* __restrict__ partial,
    float* __restrict__ out)
{
    const int p = blockIdx.x * 256 + threadIdx.x;   // d-pair 0..511
    const int j = blockIdx.y;
    const int b = blockIdx.z;
    const int d0 = 2 * p, d1 = d0 + 1;

    float phr0, phi0, phr1, phi1;
    compute_ph(pr[d0], pi[d0], phr0, phi0);
    compute_ph(pr[d1], pi[d1], phr1, phi1);
    const float q0r = qr[d0], q0i = qi[d0], q1r = qr[d1], q1i = qi[d1];

    // a = ph^TT by repeated squaring (TT = 2^7)
    float a0r = phr0, a0i = phi0, a1r = phr1, a1i = phi1;
    #pragma unroll
    for (int k = 0; k < 7; ++k) {
        float n0r = a0r * a0r - a0i * a0i, n0i = 2.f * a0r * a0i;
        float n1r = a1r * a1r - a1i * a1i, n1i = 2.f * a1r * a1i;
        a0r = n0r; a0i = n0i; a1r = n1r; a1i = n1i;
    }

    // fold: S = last; S <- a*S + P_k for k = 0..j-1 (uniform trip count)
    float s0r = lr[d0], s0i = li[d0], s1r = lr[d1], s1i = li[d1];
    const float4* pb = partial + (size_t)b * NC * NPAIR + p;
    for (int bs = 0; bs < j; bs += FOLD_BATCH) {
        float4 buf[FOLD_BATCH];
        #pragma unroll
        for (int u = 0; u < FOLD_BATCH; ++u) {
            int k = bs + u;
            int kc = (k < j) ? k : (j - 1);   // clamp: always a valid address
            buf[u] = pb[(size_t)kc * NPAIR];
        }
        #pragma unroll
        for (int u = 0; u < FOLD_BATCH; ++u) {
            int k = bs + u;
            if (k < j) {
                float n0r = fmaf(a0r, s0r, fmaf(-a0i, s0i, buf[u].x));
                float n0i = fmaf(a0i, s0r, fmaf( a0r, s0i, buf[u].y));
                float n1r = fmaf(a1r, s1r, fmaf(-a1i, s1i, buf[u].z));
                float n1i = fmaf(a1i, s1r, fmaf( a1r, s1i, buf[u].w));
                s0r = n0r; s0i = n0i; s1r = n1r; s1i = n1i;
            }
        }
    }

    // replay chunk from true start state; double-buffered load/compute/store
    const size_t rowbase = (size_t)b * LL + (size_t)j * TT;
    const float2* xp = (const float2*)(x + rowbase * DD) + p;
    float2* op = (float2*)(out + rowbase * DD) + p;

    float2 bufA[8], bufB[8];
    LD8(bufA, 0);  LD8(bufB, 1);
    CP8F(bufA);  ST8(bufA, 0);  LD8(bufA, 2);
    CP8F(bufB);  ST8(bufB, 1);  LD8(bufB, 3);
    CP8F(bufA);  ST8(bufA, 2);  LD8(bufA, 4);
    CP8F(bufB);  ST8(bufB, 3);  LD8(bufB, 5);
    CP8F(bufA);  ST8(bufA, 4);  LD8(bufA, 6);
    CP8F(bufB);  ST8(bufB, 5);  LD8(bufB, 7);
    CP8F(bufA);  ST8(bufA, 6);  LD8(bufA, 8);
    CP8F(bufB);  ST8(bufB, 7);  LD8(bufB, 9);
    CP8F(bufA);  ST8(bufA, 8);  LD8(bufA, 10);
    CP8F(bufB);  ST8(bufB, 9);  LD8(bufB, 11);
    CP8F(bufA);  ST8(bufA, 10); LD8(bufA, 12);
    CP8F(bufB);  ST8(bufB, 11); LD8(bufB, 13);
    CP8F(bufA);  ST8(bufA, 12); LD8(bufA, 14);
    CP8F(bufB);  ST8(bufB, 13); LD8(bufB, 15);
    CP8F(bufA);  ST8(bufA, 14);
    CP8F(bufB);  ST8(bufB, 15);
}

extern "C" void kernel_launch(void* const* d_in, const int* in_sizes, int n_in,
                              void* d_out, int out_size, void* d_ws, size_t ws_size,
                              hipStream_t stream) {
    const float* x  = (const float*)d_in[0];
    const float* pr = (const float*)d_in[1];
    const float* pi = (const float*)d_in[2];
    const float* qr = (const float*)d_in[3];
    const float* qi = (const float*)d_in[4];
    const float* lr = (const float*)d_in[5];
    const float* li = (const float*)d_in[6];
    float* out = (float*)d_out;

    float4* partial = (float4*)d_ws;   // BB*NC*NPAIR float4 = 1 MB

    dim3 grid(NPAIR / 256, NC, BB);    // 2 x 64 x 2 = 256 blocks
    k_partial<<<grid, 256, 0, stream>>>(x, pr, pi, qr, qi, partial);
    k_final<<<grid, 256, 0, stream>>>(x, pr, pi, qr, qi, lr, li, partial, out);
}